// Round 1
// baseline (676.202 us; speedup 1.0000x reference)
//
#include <hip/hip_runtime.h>
#include <hip/hip_bf16.h>

#define DIMC 512
#define LEN  2048
#define NH   16
#define HD   32
#define RR   32

// ---------------------------------------------------------------------------
// conv-as-GEMM: out[b,co,l] = bias[co] + sum_{ci,kk} x[b,ci,l+kk-(KK-1)] * w[co,ci,kk]
// Tiles: BM=128 (co), BN=64 (l), BK=16, 256 threads, 8x4 per thread.
// ---------------------------------------------------------------------------
template<int KK>
__global__ __launch_bounds__(256) void conv_gemm_kernel(
    const float* __restrict__ x, const float* __restrict__ w,
    const float* __restrict__ bias, float* __restrict__ out)
{
    constexpr int BM = 128, BN = 64, BK = 16;
    const int Ktot = DIMC * KK;
    const int b  = blockIdx.z;
    const int m0 = blockIdx.y * BM;
    const int n0 = blockIdx.x * BN;
    const int tid = threadIdx.x;
    const int tx = tid & 15, ty = tid >> 4;

    __shared__ float As[BK][BM];
    __shared__ float Bs[BK][BN];

    const float* xb = x + (size_t)b * DIMC * LEN;

    float acc[8][4];
    #pragma unroll
    for (int i = 0; i < 8; ++i)
        #pragma unroll
        for (int j = 0; j < 4; ++j) acc[i][j] = 0.f;

    const int arow = tid >> 2;        // 0..63
    const int ajj  = (tid & 3) * 4;   // 0,4,8,12
    const int bn   = tid & 63;        // 0..63
    const int bp   = tid >> 6;        // 0..3

    for (int p0 = 0; p0 < Ktot; p0 += BK) {
        // A tile (weights, K-contiguous), transpose-store into As[k][m]
        {
            float4 a4 = *reinterpret_cast<const float4*>(w + (size_t)(m0 + arow) * Ktot + p0 + ajj);
            As[ajj+0][arow] = a4.x; As[ajj+1][arow] = a4.y;
            As[ajj+2][arow] = a4.z; As[ajj+3][arow] = a4.w;
            float4 a5 = *reinterpret_cast<const float4*>(w + (size_t)(m0 + arow + 64) * Ktot + p0 + ajj);
            As[ajj+0][arow+64] = a5.x; As[ajj+1][arow+64] = a5.y;
            As[ajj+2][arow+64] = a5.z; As[ajj+3][arow+64] = a5.w;
        }
        // B tile: implicit shifted x
        #pragma unroll
        for (int pp = bp; pp < BK; pp += 4) {
            int p = p0 + pp;
            int ci, off;
            if constexpr (KK == 3) { ci = p / 3; off = p - ci * 3 - 2; }
            else                   { ci = p;     off = 0; }
            int l = n0 + bn + off;
            Bs[pp][bn] = (l >= 0) ? xb[(size_t)ci * LEN + l] : 0.f;
        }
        __syncthreads();
        #pragma unroll
        for (int kp = 0; kp < BK; ++kp) {
            float a[8], bb[4];
            #pragma unroll
            for (int i = 0; i < 8; ++i) a[i] = As[kp][ty*8 + i];
            #pragma unroll
            for (int j = 0; j < 4; ++j) bb[j] = Bs[kp][tx*4 + j];
            #pragma unroll
            for (int i = 0; i < 8; ++i)
                #pragma unroll
                for (int j = 0; j < 4; ++j)
                    acc[i][j] += a[i] * bb[j];
        }
        __syncthreads();
    }
    #pragma unroll
    for (int i = 0; i < 8; ++i) {
        int co = m0 + ty*8 + i;
        float bv = (bias != nullptr) ? bias[co] : 0.f;
        float4 r;
        r.x = acc[i][0] + bv; r.y = acc[i][1] + bv;
        r.z = acc[i][2] + bv; r.w = acc[i][3] + bv;
        *reinterpret_cast<float4*>(out + ((size_t)b * DIMC + co) * LEN + n0 + tx*4) = r;
    }
}

// ---------------------------------------------------------------------------
// sketch: phi[b,h,l,r] = ((q'·G1[:,r]) * (q'·G2[:,r]) / sqrt(R))^2,
//         q'[d] = gamma * q[b, h*HD+d, l] + beta
// block: 256 thr = 32 r x 8 l; grid (L/8, H, B)
// ---------------------------------------------------------------------------
__global__ __launch_bounds__(256) void sketch_kernel(
    const float* __restrict__ qk, const float* __restrict__ G1,
    const float* __restrict__ G2, const float* __restrict__ gamma,
    const float* __restrict__ beta, float* __restrict__ phi)
{
    __shared__ float g1s[HD][RR];
    __shared__ float g2s[HD][RR];
    __shared__ float qs[8][HD + 1];
    const int b = blockIdx.z, h = blockIdx.y;
    const int l0 = blockIdx.x * 8;
    const int tid = threadIdx.x;
    for (int i = tid; i < HD * RR; i += 256) {
        g1s[i >> 5][i & 31] = G1[i];
        g2s[i >> 5][i & 31] = G2[i];
    }
    const float ga = gamma[0], be = beta[0];
    {
        const int dd = tid >> 3, li = tid & 7;
        qs[li][dd] = ga * qk[((size_t)b * DIMC + h * HD + dd) * LEN + l0 + li] + be;
    }
    __syncthreads();
    const int r = tid & 31, li = tid >> 5;
    float a = 0.f, c = 0.f;
    #pragma unroll
    for (int dd = 0; dd < HD; ++dd) {
        float qv = qs[li][dd];
        a += qv * g1s[dd][r];
        c += qv * g2s[dd][r];
    }
    float hh = a * c * 0.17677669529663687f;  // 1/sqrt(32)
    phi[((size_t)(b * NH + h) * LEN + l0 + li) * RR + r] = hh * hh;
}

// ---------------------------------------------------------------------------
// S_kv[b,h,r,d] = sum_l phi_k[b,h,l,r] * v[b,h*HD+d,l];  sk[b,h,r] = sum_l phi_k
// grid (L/256, H, B), 256 thr; partials via atomicAdd (S_kv pre-zeroed).
// ---------------------------------------------------------------------------
__global__ __launch_bounds__(256) void skv_kernel(
    const float* __restrict__ phi_k, const float* __restrict__ v,
    float* __restrict__ Skv, float* __restrict__ sk)
{
    const int b = blockIdx.z, h = blockIdx.y;
    const int l0 = blockIdx.x * 256;
    const int tid = threadIdx.x;
    __shared__ float ps[64][RR];
    __shared__ float vs[64][HD + 1];
    const int r  = tid >> 3;        // 0..31
    const int d4 = (tid & 7) * 4;   // 0..28
    float acc[4] = {0.f, 0.f, 0.f, 0.f};
    float skacc = 0.f;
    const float* pk = phi_k + ((size_t)(b * NH + h) * LEN + l0) * RR;
    const float* vb = v + ((size_t)b * DIMC + h * HD) * LEN + l0;
    for (int c = 0; c < 4; ++c) {
        for (int i = tid; i < 64 * 32; i += 256) {
            ps[i >> 5][i & 31] = pk[c * 64 * 32 + i];
            int dd = i >> 6, lc = i & 63;
            vs[lc][dd] = vb[(size_t)dd * LEN + c * 64 + lc];
        }
        __syncthreads();
        #pragma unroll 8
        for (int lc = 0; lc < 64; ++lc) {
            float pv = ps[lc][r];
            skacc += pv;
            #pragma unroll
            for (int j = 0; j < 4; ++j) acc[j] += pv * vs[lc][d4 + j];
        }
        __syncthreads();
    }
    const size_t base = (size_t)(b * NH + h) * RR + r;
    float* Sp = Skv + base * HD + d4;
    #pragma unroll
    for (int j = 0; j < 4; ++j) atomicAdd(Sp + j, acc[j]);
    if ((tid & 7) == 0) atomicAdd(sk + base, skacc);
}

// ---------------------------------------------------------------------------
// o_buf[b,l,h*HD+d] = (sum_r phi_q[l,r] Skv[r,d]) / (sum_r phi_q[l,r] sk[r] + 1e-6)
// block: 256 thr = 32 d x 8 l; grid (L/8, H, B)
// ---------------------------------------------------------------------------
__global__ __launch_bounds__(256) void onorm_kernel(
    const float* __restrict__ phi_q, const float* __restrict__ Skv,
    const float* __restrict__ sk, float* __restrict__ o_buf)
{
    __shared__ float Ss[RR][HD];
    __shared__ float sks[RR];
    __shared__ float ph[8][RR + 1];
    const int b = blockIdx.z, h = blockIdx.y;
    const int l0 = blockIdx.x * 8;
    const int tid = threadIdx.x;
    const int bh = b * NH + h;
    for (int i = tid; i < RR * HD; i += 256) Ss[i >> 5][i & 31] = Skv[(size_t)bh * RR * HD + i];
    if (tid < RR) sks[tid] = sk[(size_t)bh * RR + tid];
    {
        const int r = tid & 31, li = tid >> 5;
        ph[li][r] = phi_q[((size_t)bh * LEN + l0 + li) * RR + r];
    }
    __syncthreads();
    const int d = tid & 31, li = tid >> 5;
    float num = 0.f, den = 0.f;
    #pragma unroll
    for (int r = 0; r < RR; ++r) {
        float p = ph[li][r];
        num += p * Ss[r][d];
        den += p * sks[r];
    }
    o_buf[((size_t)b * LEN + l0 + li) * DIMC + h * HD + d] = num / (den + 1e-6f);
}

// ---------------------------------------------------------------------------
// proj: out[m,n] = bias[n] + sum_c A[m,c] * W[n,c];  M=B*L, N=K=512
// Tiles 128x64x16, 256 thr, 8x4 per thread.
// ---------------------------------------------------------------------------
__global__ __launch_bounds__(256) void proj_gemm_kernel(
    const float* __restrict__ A, const float* __restrict__ W,
    const float* __restrict__ bias, float* __restrict__ out)
{
    constexpr int BM = 128, BN = 64, BK = 16;
    const int n0 = blockIdx.x * BN;
    const int m0 = blockIdx.y * BM;
    const int tid = threadIdx.x;
    const int tx = tid & 15, ty = tid >> 4;
    __shared__ float As[BK][BM];
    __shared__ float Bs[BK][BN];
    float acc[8][4];
    #pragma unroll
    for (int i = 0; i < 8; ++i)
        #pragma unroll
        for (int j = 0; j < 4; ++j) acc[i][j] = 0.f;

    const int arow = tid >> 2;
    const int ajj  = (tid & 3) * 4;

    for (int c0 = 0; c0 < DIMC; c0 += BK) {
        {
            float4 a4 = *reinterpret_cast<const float4*>(A + (size_t)(m0 + arow) * DIMC + c0 + ajj);
            As[ajj+0][arow] = a4.x; As[ajj+1][arow] = a4.y;
            As[ajj+2][arow] = a4.z; As[ajj+3][arow] = a4.w;
            float4 a5 = *reinterpret_cast<const float4*>(A + (size_t)(m0 + arow + 64) * DIMC + c0 + ajj);
            As[ajj+0][arow+64] = a5.x; As[ajj+1][arow+64] = a5.y;
            As[ajj+2][arow+64] = a5.z; As[ajj+3][arow+64] = a5.w;
        }
        {
            float4 b4 = *reinterpret_cast<const float4*>(W + (size_t)(n0 + arow) * DIMC + c0 + ajj);
            Bs[ajj+0][arow] = b4.x; Bs[ajj+1][arow] = b4.y;
            Bs[ajj+2][arow] = b4.z; Bs[ajj+3][arow] = b4.w;
        }
        __syncthreads();
        #pragma unroll
        for (int kp = 0; kp < BK; ++kp) {
            float a[8], bb[4];
            #pragma unroll
            for (int i = 0; i < 8; ++i) a[i] = As[kp][ty*8 + i];
            #pragma unroll
            for (int j = 0; j < 4; ++j) bb[j] = Bs[kp][tx*4 + j];
            #pragma unroll
            for (int i = 0; i < 8; ++i)
                #pragma unroll
                for (int j = 0; j < 4; ++j)
                    acc[i][j] += a[i] * bb[j];
        }
        __syncthreads();
    }
    float4 bv = *reinterpret_cast<const float4*>(bias + n0 + tx*4);
    #pragma unroll
    for (int i = 0; i < 8; ++i) {
        float4 r;
        r.x = acc[i][0] + bv.x; r.y = acc[i][1] + bv.y;
        r.z = acc[i][2] + bv.z; r.w = acc[i][3] + bv.w;
        *reinterpret_cast<float4*>(out + (size_t)(m0 + ty*8 + i) * DIMC + n0 + tx*4) = r;
    }
}

// ---------------------------------------------------------------------------
extern "C" void kernel_launch(void* const* d_in, const int* in_sizes, int n_in,
                              void* d_out, int out_size, void* d_ws, size_t ws_size,
                              hipStream_t stream)
{
    const float* x       = (const float*)d_in[0];
    const float* q_w     = (const float*)d_in[1];
    const float* q_b     = (const float*)d_in[2];
    const float* k_w     = (const float*)d_in[3];
    const float* k_b     = (const float*)d_in[4];
    const float* v_w     = (const float*)d_in[5];
    const float* proj_w  = (const float*)d_in[6];
    const float* proj_b  = (const float*)d_in[7];
    const float* gamma_q = (const float*)d_in[8];
    const float* beta_q  = (const float*)d_in[9];
    const float* gamma_k = (const float*)d_in[10];
    const float* beta_k  = (const float*)d_in[11];
    const float* G1q     = (const float*)d_in[12];
    const float* G2q     = (const float*)d_in[13];
    const float* G1k     = (const float*)d_in[14];
    const float* G2k     = (const float*)d_in[15];

    float* ws = (float*)d_ws;
    const size_t SZ = (size_t)2 * DIMC * LEN;  // 2,097,152 floats per [B,DIM,L] buffer
    float* q     = ws;
    float* k     = ws + SZ;
    float* v     = ws + 2 * SZ;
    float* phi_q = ws + 3 * SZ;
    float* phi_k = ws + 4 * SZ;
    float* Skv   = ws + 5 * SZ;                       // [B,H,R,HD] = 32768
    float* sk    = Skv + (size_t)2 * NH * RR * HD;    // [B,H,R]    = 1024
    float* o_buf = q;  // q is dead after sketch_q; reuse for o (saves ws)

    dim3 cgrid(LEN / 64, DIMC / 128, 2);
    conv_gemm_kernel<3><<<cgrid, 256, 0, stream>>>(x, q_w, q_b, q);
    conv_gemm_kernel<3><<<cgrid, 256, 0, stream>>>(x, k_w, k_b, k);
    conv_gemm_kernel<1><<<cgrid, 256, 0, stream>>>(x, v_w, nullptr, v);

    dim3 sgrid(LEN / 8, NH, 2);
    sketch_kernel<<<sgrid, 256, 0, stream>>>(q, G1q, G2q, gamma_q, beta_q, phi_q);
    sketch_kernel<<<sgrid, 256, 0, stream>>>(k, G1k, G2k, gamma_k, beta_k, phi_k);

    hipMemsetAsync(Skv, 0, (size_t)(2 * NH * RR * HD + 2 * NH * RR) * sizeof(float), stream);
    dim3 kgrid(LEN / 256, NH, 2);
    skv_kernel<<<kgrid, 256, 0, stream>>>(phi_k, v, Skv, sk);

    onorm_kernel<<<sgrid, 256, 0, stream>>>(phi_q, Skv, sk, o_buf);

    dim3 pgrid(DIMC / 64, (2 * LEN) / 128);
    proj_gemm_kernel<<<pgrid, 256, 0, stream>>>(o_buf, proj_w, proj_b, (float*)d_out);
}

// Round 3
// 254.906 us; speedup vs baseline: 2.6528x; 2.6528x over previous
//
#include <hip/hip_runtime.h>
#include <hip/hip_bf16.h>

#define DIMC 512
#define LEN  2048
#define NH   16
#define HD   32
#define RR   32

typedef __bf16 bf8_t __attribute__((ext_vector_type(8)));
typedef float  f4_t  __attribute__((ext_vector_type(4)));

__device__ __forceinline__ void gload16(const void* g, void* l) {
    __builtin_amdgcn_global_load_lds(
        (const __attribute__((address_space(1))) unsigned int*)g,
        (__attribute__((address_space(3))) unsigned int*)l, 16, 0, 0);
}

// ---------------------------------------------------------------------------
// split_x: x[b][ci][L] fp32 -> xTh/xTl[b][l+2][ci] bf16 (rows 0,1 zero pad)
// ---------------------------------------------------------------------------
__global__ __launch_bounds__(256) void split_x_kernel(
    const float* __restrict__ x, __bf16* __restrict__ xTh, __bf16* __restrict__ xTl)
{
    __shared__ float tile[64][65];
    const int b  = blockIdx.z;
    const int l0 = blockIdx.x * 64;
    const int c0 = blockIdx.y * 64;
    const int tid = threadIdx.x;
    #pragma unroll
    for (int it = 0; it < 4; ++it) {
        int cl = (tid >> 4) + it * 16;
        int ll = (tid & 15) * 4;
        float4 v4 = *reinterpret_cast<const float4*>(
            x + ((size_t)b * DIMC + c0 + cl) * LEN + l0 + ll);
        tile[cl][ll+0] = v4.x; tile[cl][ll+1] = v4.y;
        tile[cl][ll+2] = v4.z; tile[cl][ll+3] = v4.w;
    }
    __syncthreads();
    const int lr = tid >> 2;
    const int cb = (tid & 3) * 16;
    size_t base = ((size_t)b * 2050 + l0 + lr + 2) * DIMC + c0 + cb;
    #pragma unroll
    for (int e = 0; e < 16; ++e) {
        float f = tile[cb + e][lr];
        __bf16 h = (__bf16)f;
        xTh[base + e] = h;
        xTl[base + e] = (__bf16)(f - (float)h);
    }
    if (blockIdx.x == 0 && blockIdx.y == 0) {
        size_t pb = (size_t)b * 2050 * DIMC;
        #pragma unroll
        for (int e = 0; e < 4; ++e) {
            int p = tid * 4 + e;  // 1024 = 2 rows * 512
            xTh[pb + p] = (__bf16)0.f;
            xTl[pb + p] = (__bf16)0.f;
        }
    }
}

// ---------------------------------------------------------------------------
// split_w: q_w/k_w [co][ci][3], v_w [co][ci] -> Wr[1536][3][512] bf16 hi/lo
// row m: 0-511 q, 512-1023 k, 1024-1535 v (only kk=2 slot used for v)
// ---------------------------------------------------------------------------
__global__ __launch_bounds__(256) void split_w_kernel(
    const float* __restrict__ qw, const float* __restrict__ kw,
    const float* __restrict__ vw, __bf16* __restrict__ Wrh, __bf16* __restrict__ Wrl)
{
    int idx = blockIdx.x * 256 + threadIdx.x;   // < 1536*1536
    int m   = idx / 1536;
    int rem = idx - m * 1536;
    int kk  = rem >> 9;
    int ci  = rem & 511;
    float f;
    if (m < 512)       f = qw[((size_t)m * 512 + ci) * 3 + kk];
    else if (m < 1024) f = kw[((size_t)(m - 512) * 512 + ci) * 3 + kk];
    else               f = (kk == 2) ? vw[(size_t)(m - 1024) * 512 + ci] : 0.f;
    __bf16 h = (__bf16)f;
    Wrh[idx] = h;
    Wrl[idx] = (__bf16)(f - (float)h);
}

__global__ __launch_bounds__(256) void split_pw_kernel(
    const float* __restrict__ pw, __bf16* __restrict__ pwh, __bf16* __restrict__ pwl)
{
    int idx = blockIdx.x * 256 + threadIdx.x;   // < 512*512
    float f = pw[idx];
    __bf16 h = (__bf16)f;
    pwh[idx] = h;
    pwl[idx] = (__bf16)(f - (float)h);
}

// ---------------------------------------------------------------------------
// conv_mfma: C[mg][l] = sum_kk sum_ci Wr[mg][kk][ci] * xT[l+kk][ci]  (+bias)
// BM=128 BN=64 BK=32; 4 waves of 64x32; bf16x3 split accumulation.
// ---------------------------------------------------------------------------
__global__ __launch_bounds__(256) void conv_mfma_kernel(
    const __bf16* __restrict__ xTh, const __bf16* __restrict__ xTl,
    const __bf16* __restrict__ Wrh, const __bf16* __restrict__ Wrl,
    const float* __restrict__ q_b, const float* __restrict__ k_b,
    float* __restrict__ q, float* __restrict__ k, float* __restrict__ v,
    int m_off, int kks)
{
    __shared__ __bf16 sAh[128 * 32], sAl[128 * 32], sBh[64 * 32], sBl[64 * 32];
    const int b   = blockIdx.z;
    const int mg  = m_off + blockIdx.y * 128;
    const int n0  = blockIdx.x * 64;
    const int tid = threadIdx.x;
    const int wave = tid >> 6, lane = tid & 63;
    const int wm = wave >> 1, wn = wave & 1;
    const int lr = lane & 15, k8 = lane >> 4;

    const __bf16* xh = xTh + (size_t)b * 2050 * DIMC;
    const __bf16* xl = xTl + (size_t)b * 2050 * DIMC;

    f4_t acc[4][2];
    #pragma unroll
    for (int i = 0; i < 4; ++i)
        #pragma unroll
        for (int j = 0; j < 2; ++j)
            #pragma unroll
            for (int e = 0; e < 4; ++e) acc[i][j][e] = 0.f;

    const int sr0 = tid >> 2;                         // 0..63
    const int ss  = tid & 3;
    const int sk0 = ((ss ^ ((sr0 >> 1) & 3)) << 3);   // element offset
    const int sr1 = sr0 + 64;
    const int sk1 = ((ss ^ ((sr1 >> 1) & 3)) << 3);

    for (int kk = kks; kk < 3; ++kk) {
        const __bf16* wAh = Wrh + (size_t)mg * 1536 + kk * 512;
        const __bf16* wAl = Wrl + (size_t)mg * 1536 + kk * 512;
        const __bf16* xbh = xh + (size_t)(n0 + kk) * DIMC;
        const __bf16* xbl = xl + (size_t)(n0 + kk) * DIMC;
        for (int k0 = 0; k0 < 512; k0 += 32) {
            gload16(wAh + (size_t)sr0 * 1536 + k0 + sk0, (char*)sAh + tid * 16);
            gload16(wAh + (size_t)sr1 * 1536 + k0 + sk1, (char*)sAh + (256 + tid) * 16);
            gload16(wAl + (size_t)sr0 * 1536 + k0 + sk0, (char*)sAl + tid * 16);
            gload16(wAl + (size_t)sr1 * 1536 + k0 + sk1, (char*)sAl + (256 + tid) * 16);
            gload16(xbh + (size_t)sr0 * DIMC + k0 + sk0, (char*)sBh + tid * 16);
            gload16(xbl + (size_t)sr0 * DIMC + k0 + sk0, (char*)sBl + tid * 16);
            __syncthreads();
            bf8_t ah[4], al[4], bh[2], bl[2];
            #pragma unroll
            for (int i = 0; i < 4; ++i) {
                int row = wm * 64 + i * 16 + lr;
                int off = row * 64 + ((k8 ^ ((row >> 1) & 3)) << 4);
                ah[i] = *(const bf8_t*)((const char*)sAh + off);
                al[i] = *(const bf8_t*)((const char*)sAl + off);
            }
            #pragma unroll
            for (int j = 0; j < 2; ++j) {
                int row = wn * 32 + j * 16 + lr;
                int off = row * 64 + ((k8 ^ ((row >> 1) & 3)) << 4);
                bh[j] = *(const bf8_t*)((const char*)sBh + off);
                bl[j] = *(const bf8_t*)((const char*)sBl + off);
            }
            #pragma unroll
            for (int i = 0; i < 4; ++i)
                #pragma unroll
                for (int j = 0; j < 2; ++j) {
                    acc[i][j] = __builtin_amdgcn_mfma_f32_16x16x32_bf16(ah[i], bh[j], acc[i][j], 0, 0, 0);
                    acc[i][j] = __builtin_amdgcn_mfma_f32_16x16x32_bf16(ah[i], bl[j], acc[i][j], 0, 0, 0);
                    acc[i][j] = __builtin_amdgcn_mfma_f32_16x16x32_bf16(al[i], bh[j], acc[i][j], 0, 0, 0);
                }
            __syncthreads();
        }
    }
    const int sec = mg >> 9;  // 0:q 1:k 2:v
    float* outp = (sec == 0) ? q : (sec == 1) ? k : v;
    const float* bp = (sec == 0) ? q_b : (sec == 1) ? k_b : nullptr;
    const int cob = mg & 511;
    #pragma unroll
    for (int i = 0; i < 4; ++i)
        #pragma unroll
        for (int r = 0; r < 4; ++r) {
            int co = cob + wm * 64 + i * 16 + k8 * 4 + r;
            float bv = bp ? bp[co] : 0.f;
            float* orow = outp + ((size_t)b * DIMC + co) * LEN;
            #pragma unroll
            for (int j = 0; j < 2; ++j)
                orow[n0 + wn * 32 + j * 16 + lr] = acc[i][j][r] + bv;
        }
}

// ---------------------------------------------------------------------------
// proj_mfma: out[m][n] = sum_c o[m][c] pw[n][c] + pb[n];  M=4096 N=512 K=512
// ---------------------------------------------------------------------------
__global__ __launch_bounds__(256) void proj_mfma_kernel(
    const __bf16* __restrict__ oh, const __bf16* __restrict__ ol,
    const __bf16* __restrict__ pwh, const __bf16* __restrict__ pwl,
    const float* __restrict__ pb, float* __restrict__ out)
{
    __shared__ __bf16 sAh[128 * 32], sAl[128 * 32], sBh[64 * 32], sBl[64 * 32];
    const int m0  = blockIdx.y * 128;
    const int n0  = blockIdx.x * 64;
    const int tid = threadIdx.x;
    const int wave = tid >> 6, lane = tid & 63;
    const int wm = wave >> 1, wn = wave & 1;
    const int lr = lane & 15, k8 = lane >> 4;

    f4_t acc[4][2];
    #pragma unroll
    for (int i = 0; i < 4; ++i)
        #pragma unroll
        for (int j = 0; j < 2; ++j)
            #pragma unroll
            for (int e = 0; e < 4; ++e) acc[i][j][e] = 0.f;

    const int sr0 = tid >> 2;
    const int ss  = tid & 3;
    const int sk0 = ((ss ^ ((sr0 >> 1) & 3)) << 3);
    const int sr1 = sr0 + 64;
    const int sk1 = ((ss ^ ((sr1 >> 1) & 3)) << 3);

    for (int k0 = 0; k0 < 512; k0 += 32) {
        gload16(oh + (size_t)(m0 + sr0) * DIMC + k0 + sk0, (char*)sAh + tid * 16);
        gload16(oh + (size_t)(m0 + sr1) * DIMC + k0 + sk1, (char*)sAh + (256 + tid) * 16);
        gload16(ol + (size_t)(m0 + sr0) * DIMC + k0 + sk0, (char*)sAl + tid * 16);
        gload16(ol + (size_t)(m0 + sr1) * DIMC + k0 + sk1, (char*)sAl + (256 + tid) * 16);
        gload16(pwh + (size_t)(n0 + sr0) * DIMC + k0 + sk0, (char*)sBh + tid * 16);
        gload16(pwl + (size_t)(n0 + sr0) * DIMC + k0 + sk0, (char*)sBl + tid * 16);
        __syncthreads();
        bf8_t ah[4], al[4], bh[2], bl[2];
        #pragma unroll
        for (int i = 0; i < 4; ++i) {
            int row = wm * 64 + i * 16 + lr;
            int off = row * 64 + ((k8 ^ ((row >> 1) & 3)) << 4);
            ah[i] = *(const bf8_t*)((const char*)sAh + off);
            al[i] = *(const bf8_t*)((const char*)sAl + off);
        }
        #pragma unroll
        for (int j = 0; j < 2; ++j) {
            int row = wn * 32 + j * 16 + lr;
            int off = row * 64 + ((k8 ^ ((row >> 1) & 3)) << 4);
            bh[j] = *(const bf8_t*)((const char*)sBh + off);
            bl[j] = *(const bf8_t*)((const char*)sBl + off);
        }
        #pragma unroll
        for (int i = 0; i < 4; ++i)
            #pragma unroll
            for (int j = 0; j < 2; ++j) {
                acc[i][j] = __builtin_amdgcn_mfma_f32_16x16x32_bf16(ah[i], bh[j], acc[i][j], 0, 0, 0);
                acc[i][j] = __builtin_amdgcn_mfma_f32_16x16x32_bf16(ah[i], bl[j], acc[i][j], 0, 0, 0);
                acc[i][j] = __builtin_amdgcn_mfma_f32_16x16x32_bf16(al[i], bh[j], acc[i][j], 0, 0, 0);
            }
        __syncthreads();
    }
    #pragma unroll
    for (int j = 0; j < 2; ++j) {
        int n = n0 + wn * 32 + j * 16 + lr;
        float bv = pb[n];
        #pragma unroll
        for (int i = 0; i < 4; ++i)
            #pragma unroll
            for (int r = 0; r < 4; ++r) {
                int m = m0 + wm * 64 + i * 16 + k8 * 4 + r;
                out[(size_t)m * DIMC + n] = acc[i][j][r] + bv;
            }
    }
}

// ---------------------------------------------------------------------------
// sketch: phi[b,h,l,r] = ((q'.G1[:,r]) * (q'.G2[:,r]) / sqrt(R))^2
// ---------------------------------------------------------------------------
__global__ __launch_bounds__(256) void sketch_kernel(
    const float* __restrict__ qk, const float* __restrict__ G1,
    const float* __restrict__ G2, const float* __restrict__ gamma,
    const float* __restrict__ beta, float* __restrict__ phi)
{
    __shared__ float g1s[HD][RR];
    __shared__ float g2s[HD][RR];
    __shared__ float qs[8][HD + 1];
    const int b = blockIdx.z, h = blockIdx.y;
    const int l0 = blockIdx.x * 8;
    const int tid = threadIdx.x;
    for (int i = tid; i < HD * RR; i += 256) {
        g1s[i >> 5][i & 31] = G1[i];
        g2s[i >> 5][i & 31] = G2[i];
    }
    const float ga = gamma[0], be = beta[0];
    {
        const int dd = tid >> 3, li = tid & 7;
        qs[li][dd] = ga * qk[((size_t)b * DIMC + h * HD + dd) * LEN + l0 + li] + be;
    }
    __syncthreads();
    const int r = tid & 31, li = tid >> 5;
    float a = 0.f, c = 0.f;
    #pragma unroll
    for (int dd = 0; dd < HD; ++dd) {
        float qv = qs[li][dd];
        a += qv * g1s[dd][r];
        c += qv * g2s[dd][r];
    }
    float hh = a * c * 0.17677669529663687f;  // 1/sqrt(32)
    phi[((size_t)(b * NH + h) * LEN + l0 + li) * RR + r] = hh * hh;
}

// ---------------------------------------------------------------------------
// S_kv[b,h,r,d] = sum_l phi_k[b,h,l,r] * v[b,h*HD+d,l];  sk = sum_l phi_k
// ---------------------------------------------------------------------------
__global__ __launch_bounds__(256) void skv_kernel(
    const float* __restrict__ phi_k, const float* __restrict__ v,
    float* __restrict__ Skv, float* __restrict__ sk)
{
    const int b = blockIdx.z, h = blockIdx.y;
    const int l0 = blockIdx.x * 256;
    const int tid = threadIdx.x;
    __shared__ float ps[64][RR];
    __shared__ float vs[64][HD + 1];
    const int r  = tid >> 3;
    const int d4 = (tid & 7) * 4;
    float acc[4] = {0.f, 0.f, 0.f, 0.f};
    float skacc = 0.f;
    const float* pk = phi_k + ((size_t)(b * NH + h) * LEN + l0) * RR;
    const float* vb = v + ((size_t)b * DIMC + h * HD) * LEN + l0;
    for (int c = 0; c < 4; ++c) {
        for (int i = tid; i < 64 * 32; i += 256) {
            ps[i >> 5][i & 31] = pk[c * 64 * 32 + i];
            int dd = i >> 6, lc = i & 63;
            vs[lc][dd] = vb[(size_t)dd * LEN + c * 64 + lc];
        }
        __syncthreads();
        #pragma unroll 8
        for (int lc = 0; lc < 64; ++lc) {
            float pv = ps[lc][r];
            skacc += pv;
            #pragma unroll
            for (int j = 0; j < 4; ++j) acc[j] += pv * vs[lc][d4 + j];
        }
        __syncthreads();
    }
    const size_t base = (size_t)(b * NH + h) * RR + r;
    float* Sp = Skv + base * HD + d4;
    #pragma unroll
    for (int j = 0; j < 4; ++j) atomicAdd(Sp + j, acc[j]);
    if ((tid & 7) == 0) atomicAdd(sk + base, skacc);
}

// ---------------------------------------------------------------------------
// onorm: o[b,l,h*HD+d] = (phi_q . Skv) / (phi_q . sk + 1e-6) -> bf16 hi/lo
// ---------------------------------------------------------------------------
__global__ __launch_bounds__(256) void onorm_kernel(
    const float* __restrict__ phi_q, const float* __restrict__ Skv,
    const float* __restrict__ sk, __bf16* __restrict__ o_h, __bf16* __restrict__ o_l)
{
    __shared__ float Ss[RR][HD];
    __shared__ float sks[RR];
    __shared__ float ph[8][RR + 1];
    const int b = blockIdx.z, hh = blockIdx.y;
    const int l0 = blockIdx.x * 8;
    const int tid = threadIdx.x;
    const int bh = b * NH + hh;
    for (int i = tid; i < RR * HD; i += 256) Ss[i >> 5][i & 31] = Skv[(size_t)bh * RR * HD + i];
    if (tid < RR) sks[tid] = sk[(size_t)bh * RR + tid];
    {
        const int r = tid & 31, li = tid >> 5;
        ph[li][r] = phi_q[((size_t)bh * LEN + l0 + li) * RR + r];
    }
    __syncthreads();
    const int d = tid & 31, li = tid >> 5;
    float num = 0.f, den = 0.f;
    #pragma unroll
    for (int r = 0; r < RR; ++r) {
        float p = ph[li][r];
        num += p * Ss[r][d];
        den += p * sks[r];
    }
    float val = num / (den + 1e-6f);
    __bf16 hv = (__bf16)val;
    size_t oi = ((size_t)b * LEN + l0 + li) * DIMC + hh * HD + d;
    o_h[oi] = hv;
    o_l[oi] = (__bf16)(val - (float)hv);
}

// ---------------------------------------------------------------------------
extern "C" void kernel_launch(void* const* d_in, const int* in_sizes, int n_in,
                              void* d_out, int out_size, void* d_ws, size_t ws_size,
                              hipStream_t stream)
{
    const float* x       = (const float*)d_in[0];
    const float* q_w     = (const float*)d_in[1];
    const float* q_b     = (const float*)d_in[2];
    const float* k_w     = (const float*)d_in[3];
    const float* k_b     = (const float*)d_in[4];
    const float* v_w     = (const float*)d_in[5];
    const float* proj_w  = (const float*)d_in[6];
    const float* proj_b  = (const float*)d_in[7];
    const float* gamma_q = (const float*)d_in[8];
    const float* beta_q  = (const float*)d_in[9];
    const float* gamma_k = (const float*)d_in[10];
    const float* beta_k  = (const float*)d_in[11];
    const float* G1q     = (const float*)d_in[12];
    const float* G2q     = (const float*)d_in[13];
    const float* G1k     = (const float*)d_in[14];
    const float* G2k     = (const float*)d_in[15];

    char* W = (char*)d_ws;
    constexpr size_t QKV   = (size_t)2 * DIMC * LEN * 4;     // 8 MB each
    constexpr size_t XT    = (size_t)2 * 2050 * DIMC * 2;    // 4,198,400 B
    constexpr size_t WR    = (size_t)1536 * 1536 * 2;        // 4,718,592 B
    constexpr size_t PW    = (size_t)DIMC * DIMC * 2;        // 524,288 B
    constexpr size_t SKVB  = (size_t)2 * NH * RR * HD * 4;   // 131,072 B
    constexpr size_t SKB   = (size_t)2 * NH * RR * 4;        // 4,096 B

    float*  q    = (float*)(W);
    float*  k    = (float*)(W + QKV);
    float*  v    = (float*)(W + 2 * QKV);
    __bf16* xTh  = (__bf16*)(W + 3 * QKV);
    __bf16* xTl  = (__bf16*)(W + 3 * QKV + XT);
    __bf16* Wrh  = (__bf16*)(W + 3 * QKV + 2 * XT);
    __bf16* Wrl  = (__bf16*)(W + 3 * QKV + 2 * XT + WR);
    __bf16* pwh  = (__bf16*)(W + 3 * QKV + 2 * XT + 2 * WR);
    __bf16* pwl  = (__bf16*)(W + 3 * QKV + 2 * XT + 2 * WR + PW);
    float*  Skv  = (float*)(W + 3 * QKV + 2 * XT + 2 * WR + 2 * PW);
    float*  sk   = (float*)(W + 3 * QKV + 2 * XT + 2 * WR + 2 * PW + SKVB);
    // aliases (regions dead by the time these are written):
    float*  phi_q = (float*)(W + 3 * QKV);            // over xTh+xTl (8.4 MB >= 8 MB)
    float*  phi_k = (float*)(W + 3 * QKV + 2 * XT);   // over Wrh+Wrl (9.4 MB >= 8 MB)
    __bf16* o_h   = (__bf16*)(W);                     // over q
    __bf16* o_l   = (__bf16*)(W + QKV / 2);           // over q (second half)

    split_x_kernel<<<dim3(LEN / 64, DIMC / 64, 2), 256, 0, stream>>>(x, xTh, xTl);
    split_w_kernel<<<(1536 * 1536) / 256, 256, 0, stream>>>(q_w, k_w, v_w, Wrh, Wrl);
    split_pw_kernel<<<(DIMC * DIMC) / 256, 256, 0, stream>>>(proj_w, pwh, pwl);

    // q/k conv: M=1024, K=3*512.  v conv: M=512 (rows 1024+), K=512 (kk=2 only)
    conv_mfma_kernel<<<dim3(LEN / 64, 8, 2), 256, 0, stream>>>(
        xTh, xTl, Wrh, Wrl, q_b, k_b, q, k, v, 0, 0);
    conv_mfma_kernel<<<dim3(LEN / 64, 4, 2), 256, 0, stream>>>(
        xTh, xTl, Wrh, Wrl, q_b, k_b, q, k, v, 1024, 2);

    dim3 sgrid(LEN / 8, NH, 2);
    sketch_kernel<<<sgrid, 256, 0, stream>>>(q, G1q, G2q, gamma_q, beta_q, phi_q);
    sketch_kernel<<<sgrid, 256, 0, stream>>>(k, G1k, G2k, gamma_k, beta_k, phi_k);

    hipMemsetAsync(Skv, 0, SKVB + SKB, stream);
    skv_kernel<<<dim3(LEN / 256, NH, 2), 256, 0, stream>>>(phi_k, v, Skv, sk);

    onorm_kernel<<<sgrid, 256, 0, stream>>>(phi_q, Skv, sk, o_h, o_l);

    proj_mfma_kernel<<<dim3(DIMC / 64, (2 * LEN) / 128), 256, 0, stream>>>(
        o_h, o_l, pwh, pwl, proj_b, (float*)d_out);
}